// Round 13
// baseline (426.547 us; speedup 1.0000x reference)
//
#include <hip/hip_runtime.h>

#define NN 16384
#define DD 16
#define KK 64
#define QQ 4            // queries per block
#define TPB 256
#define HIST 1024       // buckets over d2 in [0,256), width 1/4 — covers ALL pairs
#define HISTW (HIST/2)  // packed: 2 u16 counters per u32
#define LIST_MAX 768    // E[count]≈590, +7 sigma; overflow -> exact fallback
#define CAND_MAX 256

// XLA:CPU vectorized row-reduce, minor dim 16: lane halving tree. (VALIDATED r5)
__device__ __forceinline__ float halving_sumsq16(const float* v) {
    float p[16];
#pragma unroll
    for (int d = 0; d < 16; ++d) p[d] = __fmul_rn(v[d], v[d]);
    float r8[8];
#pragma unroll
    for (int j = 0; j < 8; ++j) r8[j] = __fadd_rn(p[j], p[j + 8]);
    float r4[4];
#pragma unroll
    for (int j = 0; j < 4; ++j) r4[j] = __fadd_rn(r8[j], r8[j + 4]);
    float r2[2];
#pragma unroll
    for (int j = 0; j < 2; ++j) r2[j] = __fadd_rn(r4[j], r4[j + 2]);
    return __fadd_rn(r2[0], r2[1]);
}

// d2 recipe (VALIDATED r5): f32( f32(sqi+sqj) - 2*dot ), dot = ascending-k fmaf
__device__ __forceinline__ float d2_of(const float* xi, const float* xj,
                                       float sqi, float sqj) {
    float dot = 0.0f;
#pragma unroll
    for (int d = 0; d < DD; ++d) dot = fmaf(xi[d], xj[d], dot);
    return __fsub_rn(__fadd_rn(sqi, sqj), __fmul_rn(2.0f, dot));
}

__device__ __forceinline__ int bucket_of(float d2) {
    int b = (int)__fmul_rn(d2, 4.0f);
    if (b < 0) b = 0;
    if (b >= HIST) b = HIST - 1;
    return b;
}

#define LOAD_XQ()                                                              \
    float xq[QQ][DD];                                                          \
    float sq[QQ], Tq[QQ];                                                      \
    _Pragma("unroll") for (int q = 0; q < QQ; ++q) {                           \
        const float4* p = reinterpret_cast<const float4*>(x + (iA + q) * DD);  \
        float4 a0 = p[0], a1 = p[1], a2 = p[2], a3 = p[3];                     \
        xq[q][0]=a0.x; xq[q][1]=a0.y; xq[q][2]=a0.z; xq[q][3]=a0.w;            \
        xq[q][4]=a1.x; xq[q][5]=a1.y; xq[q][6]=a1.z; xq[q][7]=a1.w;            \
        xq[q][8]=a2.x; xq[q][9]=a2.y; xq[q][10]=a2.z; xq[q][11]=a2.w;          \
        xq[q][12]=a3.x; xq[q][13]=a3.y; xq[q][14]=a3.z; xq[q][15]=a3.w;        \
        sq[q] = sqf[iA + q];                                                   \
        Tq[q] = 16.0f + sq[q] - 1.8f * sqrtf(32.0f + 4.0f * sq[q]);            \
    }

#define LOAD_XJ(j)                                                             \
    const float4* xj4 = reinterpret_cast<const float4*>(x + (j) * DD);         \
    float4 a0 = xj4[0], a1 = xj4[1], a2 = xj4[2], a3 = xj4[3];                 \
    float xj[DD] = {a0.x, a0.y, a0.z, a0.w, a1.x, a1.y, a1.z, a1.w,            \
                    a2.x, a2.y, a2.z, a2.w, a3.x, a3.y, a3.z, a3.w};

// ---------------- prep: f32 squared norms (halving tree) + copy x ----------------
__global__ void prep_kernel(const float* __restrict__ x,
                            float* __restrict__ out_x,
                            float* __restrict__ sqf) {
    int i = blockIdx.x * blockDim.x + threadIdx.x;
    if (i < NN) {
        float v[DD];
#pragma unroll
        for (int d = 0; d < DD; ++d) v[d] = x[i * DD + d];
        sqf[i] = halving_sumsq16(v);
    }
    for (int t = i; t < NN * DD; t += gridDim.x * blockDim.x) {
        out_x[t] = x[t];
    }
}

// ---------------- K1: scan only (tiny LDS -> full occupancy) ----------------
__global__ __launch_bounds__(TPB) void scan_kernel(
        const float* __restrict__ x,
        const float* __restrict__ sqf,
        unsigned int* __restrict__ ws_cnt,
        unsigned short* __restrict__ ws_list) {
    __shared__ unsigned short list[QQ][LIST_MAX];   // 6 KB
    __shared__ unsigned int s_cnt[QQ];

    const int bid = blockIdx.x;
    const int tid = threadIdx.x;
    const int lane = tid & 63;
    const int iA = bid * QQ;

    if (tid < QQ) s_cnt[tid] = 0;
    LOAD_XQ();
    __syncthreads();

    // single scan; d2 < Tq -> ballot-aggregated list append (self included)
    for (int j = tid; j < NN; j += TPB) {
        LOAD_XJ(j);
        const float sj = sqf[j];
#pragma unroll
        for (int q = 0; q < QQ; ++q) {
            float d2 = d2_of(xq[q], xj, sq[q], sj);
            bool want = d2 < Tq[q];
            unsigned long long m = __ballot(want);
            if (want) {
                int leader = __ffsll(m) - 1;
                unsigned int base = 0;
                if (lane == leader)
                    base = atomicAdd(&s_cnt[q], (unsigned int)__popcll(m));
                base = __shfl(base, leader, 64);
                unsigned int pos =
                    base + (unsigned int)__popcll(m & ((1ull << lane) - 1ull));
                if (pos < LIST_MAX) list[q][pos] = (unsigned short)j;
            }
        }
    }
    __syncthreads();

    // dump lists + raw counts to ws
    for (int q = 0; q < QQ; ++q) {
        int lc = (int)min(s_cnt[q], (unsigned int)LIST_MAX);
        unsigned short* dst = ws_list + ((long)iA + q) * LIST_MAX;
        for (int e = tid; e < lc; e += TPB) dst[e] = list[q][e];
    }
    if (tid < QQ) ws_cnt[iA + tid] = s_cnt[tid];
}

// ---------------- K2: select + rank + write ----------------
__global__ __launch_bounds__(TPB) void select_kernel(
        const float* __restrict__ x,
        const int* __restrict__ pid,
        const float* __restrict__ sqf,
        const unsigned int* __restrict__ ws_cnt,
        const unsigned short* __restrict__ ws_list,
        float* __restrict__ out_src,
        float* __restrict__ out_dst,
        float* __restrict__ out_y,
        float* __restrict__ out_ef,
        float* __restrict__ out_mask) {
    __shared__ unsigned short list[QQ][LIST_MAX];   // 6 KB
    __shared__ unsigned int hist[QQ][HISTW];        // 8 KB
    __shared__ unsigned int cand_key[QQ][CAND_MAX]; // 4 KB
    __shared__ int cand_idx[QQ][CAND_MAX];          // 4 KB
    __shared__ unsigned int wavesum[QQ][TPB / 64];
    __shared__ int s_bsel[QQ];
    __shared__ unsigned int s_excnt[QQ], s_candcnt[QQ], s_lc[QQ];
    __shared__ int s_fb[QQ];

    const int bid = blockIdx.x;
    const int tid = threadIdx.x;
    const int lane = tid & 63;
    const int w = tid >> 6;
    const int iA = bid * QQ;

    for (int t = tid; t < QQ * HISTW; t += TPB)
        ((unsigned int*)hist)[t] = 0;
    if (tid < QQ) {
        s_excnt[tid] = 0; s_candcnt[tid] = 0; s_bsel[tid] = HIST - 1;
        s_lc[tid] = min(ws_cnt[iA + tid], (unsigned int)LIST_MAX);
    }
    LOAD_XQ();
    __syncthreads();

    // stage lists from ws
    for (int q = 0; q < QQ; ++q) {
        const unsigned short* src = ws_list + ((long)iA + q) * LIST_MAX;
        const int lc = (int)s_lc[q];
        for (int e = tid; e < lc; e += TPB) list[q][e] = src[e];
    }
    __syncthreads();

    // E0: exact d2 per list entry -> hist (all entries) + exact count(<Tq)
    // (soundness guard: with an approximate scan upstream, exact_cnt >= KK+1
    //  certifies top-64 ⊆ list; with the exact scan it equals raw count)
    for (int q = 0; q < QQ; ++q) {
        const int lc = (int)s_lc[q];
        unsigned int my = 0;
        for (int e = tid; e < lc; e += TPB) {
            const int j = list[q][e];
            LOAD_XJ(j);
            float d2 = d2_of(xq[q], xj, sq[q], sqf[j]);
            my += (d2 < Tq[q]) ? 1u : 0u;
            int b = bucket_of(d2);
            atomicAdd(&hist[q][b >> 1], 1u << ((b & 1) << 4));
        }
        unsigned int v = my;
#pragma unroll
        for (int off = 1; off < 64; off <<= 1) v += __shfl_xor(v, off, 64);
        if (lane == 0 && v) atomicAdd(&s_excnt[q], v);
    }
    __syncthreads();

    if (tid < QQ)
        s_fb[tid] = (ws_cnt[iA + tid] > LIST_MAX) || (s_excnt[tid] < KK + 1);
    __syncthreads();
    const int anyfb = s_fb[0] | s_fb[1] | s_fb[2] | s_fb[3];

    // (rare) fallback: reset hist and rebuild from full rescan, self excluded
    if (anyfb) {
#pragma unroll
        for (int q = 0; q < QQ; ++q)
            if (s_fb[q])
                for (int t = tid; t < HISTW; t += TPB) hist[q][t] = 0;
        __syncthreads();
        for (int j = tid; j < NN; j += TPB) {
            LOAD_XJ(j);
            const float sj = sqf[j];
#pragma unroll
            for (int q = 0; q < QQ; ++q) {
                if (s_fb[q] && j != iA + q) {
                    float d2 = d2_of(xq[q], xj, sq[q], sj);
                    int b = bucket_of(d2);
                    atomicAdd(&hist[q][b >> 1], 1u << ((b & 1) << 4));
                }
            }
        }
    }
    __syncthreads();

    // F: prefix-scan over packed buckets -> bucket of need-th key (VALIDATED r8/r11)
    {
        unsigned int local[QQ], inc[QQ];
        unsigned int pc0[QQ], pc1[QQ], pc2[QQ], pc3[QQ];
#pragma unroll
        for (int q = 0; q < QQ; ++q) {
            unsigned int h0 = hist[q][2 * tid];
            unsigned int h1 = hist[q][2 * tid + 1];
            pc0[q] = h0 & 0xFFFFu; pc1[q] = h0 >> 16;
            pc2[q] = h1 & 0xFFFFu; pc3[q] = h1 >> 16;
            unsigned int s = pc0[q] + pc1[q] + pc2[q] + pc3[q];
            local[q] = s;
            unsigned int v = s;
#pragma unroll
            for (int off = 1; off < 64; off <<= 1) {
                unsigned int n = __shfl_up(v, off, 64);
                if (lane >= off) v += n;
            }
            inc[q] = v;
        }
        if (lane == 63)
#pragma unroll
            for (int q = 0; q < QQ; ++q) wavesum[q][w] = inc[q];
        __syncthreads();
#pragma unroll
        for (int q = 0; q < QQ; ++q) {
            const unsigned int need = s_fb[q] ? KK : (KK + 1);
            unsigned int woff = 0;
            for (int ww = 0; ww < w; ++ww) woff += wavesum[q][ww];
            unsigned int cum = inc[q] + woff;
            unsigned int prev = cum - local[q];
            if (prev < need && need <= cum) {
                unsigned int acc = prev;
                int b = 4 * tid;
                if (acc + pc0[q] < need) { acc += pc0[q]; ++b;
                    if (acc + pc1[q] < need) { acc += pc1[q]; ++b;
                        if (acc + pc2[q] < need) { acc += pc2[q]; ++b; } } }
                s_bsel[q] = b;
            }
        }
    }
    __syncthreads();

    // G: candidate gather (self excluded)
#pragma unroll
    for (int q = 0; q < QQ; ++q) {
        if (!s_fb[q]) {
            const int bsel = s_bsel[q];
            const int lc = (int)s_lc[q];
            for (int e = tid; e < lc; e += TPB) {
                const int j = list[q][e];
                LOAD_XJ(j);
                float d2 = d2_of(xq[q], xj, sq[q], sqf[j]);
                if (bucket_of(d2) <= bsel && j != iA + q) {
                    unsigned int pos = atomicAdd(&s_candcnt[q], 1u);
                    if (pos < CAND_MAX) {
                        unsigned int u = __float_as_uint(d2);
                        u ^= (u & 0x80000000u) ? 0xFFFFFFFFu : 0x80000000u;
                        cand_key[q][pos] = u;
                        cand_idx[q][pos] = j;
                    }
                }
            }
        }
    }
    if (anyfb) {
        for (int j = tid; j < NN; j += TPB) {
            LOAD_XJ(j);
            const float sj = sqf[j];
#pragma unroll
            for (int q = 0; q < QQ; ++q) {
                if (s_fb[q] && j != iA + q) {
                    float d2 = d2_of(xq[q], xj, sq[q], sj);
                    if (bucket_of(d2) <= s_bsel[q]) {
                        unsigned int pos = atomicAdd(&s_candcnt[q], 1u);
                        if (pos < CAND_MAX) {
                            unsigned int u = __float_as_uint(d2);
                            u ^= (u & 0x80000000u) ? 0xFFFFFFFFu : 0x80000000u;
                            cand_key[q][pos] = u;
                            cand_idx[q][pos] = j;
                        }
                    }
                }
            }
        }
    }
    __syncthreads();

    // H: rank by (key asc, index asc) + write outputs (VALIDATED)
    for (int q = 0; q < QQ; ++q) {
        const int iq = iA + q;
        const int mypid = pid[iq];
        int c = (int)s_candcnt[q];
        if (c > CAND_MAX) c = CAND_MAX;
        for (int t = tid; t < c; t += TPB) {
            const unsigned int kt = cand_key[q][t];
            const int jt = cand_idx[q][t];
            int rank = 0;
            for (int u = 0; u < c; ++u) {
                unsigned int ku = cand_key[q][u];
                rank += (ku < kt) || (ku == kt && cand_idx[q][u] < jt);
            }
            if (rank < KK) {
                const long e = (long)iq * KK + rank;
                out_src[e] = (float)jt;

                const float* xjp = x + jt * DD;
                float diff[DD], sum[DD];
#pragma unroll
                for (int d = 0; d < DD; ++d) {
                    float a = xjp[d], b = xq[q][d];
                    diff[d] = __fsub_rn(a, b);   // x_src - x_dst
                    sum[d]  = __fadd_rn(a, b);   // x_src + x_dst
                }
                const float s2 = halving_sumsq16(diff);    // VALIDATED tree
                const bool m = __fsqrt_rn(s2) < 6.0f;
                out_mask[e] = m ? 1.0f : 0.0f;
                const int pj = pid[jt];
                out_y[e] = (m && pj == mypid && pj > 0) ? 1.0f : 0.0f;

                float* ef = out_ef + e * (2 * DD);
#pragma unroll
                for (int d = 0; d < DD; ++d) ef[d] = m ? diff[d] : 0.0f;
#pragma unroll
                for (int d = 0; d < DD; ++d) ef[DD + d] = m ? sum[d] : 0.0f;
            }
        }
    }

    // dst column of edge_index
    for (int t = tid; t < QQ * KK; t += TPB) {
        out_dst[(long)iA * KK + t] = (float)(iA + t / KK);
    }
}

extern "C" void kernel_launch(void* const* d_in, const int* in_sizes, int n_in,
                              void* d_out, int out_size, void* d_ws, size_t ws_size,
                              hipStream_t stream) {
    const float* x = (const float*)d_in[0];
    const int* pid = (const int*)d_in[1];
    float* out = (float*)d_out;

    float* out_x   = out;                                // N*D
    float* out_src = out_x + NN * DD;                    // N*K
    float* out_dst = out_src + NN * KK;                  // N*K
    float* out_y   = out_dst + NN * KK;                  // N*K
    float* out_ef  = out_y + NN * KK;                    // N*K*2D
    float* out_mask = out_ef + (long)NN * KK * 2 * DD;   // N*K

    // ws layout: sqf f32[NN] | cnt u32[NN] | lists u16[NN][LIST_MAX] (~25.3 MB)
    float* sqf = (float*)d_ws;
    unsigned int* ws_cnt = (unsigned int*)((char*)d_ws + NN * sizeof(float));
    unsigned short* ws_list =
        (unsigned short*)((char*)d_ws + NN * sizeof(float) + NN * sizeof(unsigned int));

    prep_kernel<<<NN / 256, 256, 0, stream>>>(x, out_x, sqf);
    scan_kernel<<<NN / QQ, TPB, 0, stream>>>(x, sqf, ws_cnt, ws_list);
    select_kernel<<<NN / QQ, TPB, 0, stream>>>(x, pid, sqf, ws_cnt, ws_list,
                                               out_src, out_dst, out_y,
                                               out_ef, out_mask);
}